// Round 1
// baseline (254.194 us; speedup 1.0000x reference)
//
#include <hip/hip_runtime.h>
#include <hip/hip_bf16.h>

typedef unsigned short u16;
typedef unsigned int u32;
typedef __attribute__((ext_vector_type(8))) short bf16x8;   // 8 bf16 (4 VGPRs)
typedef __attribute__((ext_vector_type(4))) short s16x4;
typedef __attribute__((ext_vector_type(4))) float f32x4;

#define NN 4096
#define BM 128
#define BN 128
#define BK 64

__device__ __forceinline__ u16 f2bf(float f) {
    union { float f; u32 u; } v; v.f = f;
    u32 r = v.u + 0x7fffu + ((v.u >> 16) & 1u);   // RNE (inputs finite)
    return (u16)(r >> 16);
}

// ---------------- K1: deg = rowsum(A); inv_d = 1/(deg+1) ----------------
__global__ void rowsum_kernel(const float* __restrict__ A, float* __restrict__ invd) {
    const int row = blockIdx.x;
    const float4* a4 = reinterpret_cast<const float4*>(A + (size_t)row * NN);
    float s = 0.f;
    #pragma unroll
    for (int i = 0; i < 4; ++i) {
        float4 v = a4[threadIdx.x + i * 256];
        s += v.x + v.y + v.z + v.w;
    }
    #pragma unroll
    for (int off = 32; off > 0; off >>= 1) s += __shfl_down(s, off, 64);
    __shared__ float ws[4];
    if ((threadIdx.x & 63) == 0) ws[threadIdx.x >> 6] = s;
    __syncthreads();
    if (threadIdx.x == 0) {
        float t = ws[0] + ws[1] + ws[2] + ws[3];
        invd[row] = 1.0f / (t + 1.0f);
    }
}

// ------- K2: temp = 0.5*h + 0.5*(A + I)*inv_d[col]  -> bf16 [M][K] -------
__global__ void make_temp_kernel(const float* __restrict__ A, const float* __restrict__ h,
                                 const float* __restrict__ invd, u16* __restrict__ T) {
    const size_t g = ((size_t)blockIdx.x * 256 + threadIdx.x) * 8;
    const int row = (int)(g >> 12);
    const int col = (int)(g & 4095);
    const float4* a4 = reinterpret_cast<const float4*>(A + g);
    const float4* h4 = reinterpret_cast<const float4*>(h + g);
    const float4* d4 = reinterpret_cast<const float4*>(invd + col);
    float4 a0 = a4[0], a1 = a4[1];
    float4 h0 = h4[0], h1 = h4[1];
    float4 dd0 = d4[0], dd1 = d4[1];
    float av[8] = {a0.x,a0.y,a0.z,a0.w,a1.x,a1.y,a1.z,a1.w};
    float hv[8] = {h0.x,h0.y,h0.z,h0.w,h1.x,h1.y,h1.z,h1.w};
    float dv[8] = {dd0.x,dd0.y,dd0.z,dd0.w,dd1.x,dd1.y,dd1.z,dd1.w};
    bf16x8 o;
    #pragma unroll
    for (int j = 0; j < 8; ++j) {
        float aa = av[j] + ((col + j == row) ? 1.0f : 0.0f);
        float t = 0.5f * hv[j] + 0.5f * aa * dv[j];
        o[j] = (short)f2bf(t);
    }
    *reinterpret_cast<bf16x8*>(T + g) = o;
}

// --------- K3: Wt[n][k] = bf16(W[k][n])  (LDS 64x64 tile transpose) ---------
__global__ void transposeW_kernel(const float* __restrict__ W, u16* __restrict__ Wt) {
    __shared__ float tile[64][65];
    const int nt = blockIdx.x & 63;
    const int kt = blockIdx.x >> 6;
    const int k0 = kt * 64, n0 = nt * 64;
    const int tr = threadIdx.x >> 4;          // 0..15
    const int tc = (threadIdx.x & 15) * 4;    // 0..60
    #pragma unroll
    for (int rr = 0; rr < 64; rr += 16) {
        float4 v = *reinterpret_cast<const float4*>(&W[(size_t)(k0 + tr + rr) * NN + n0 + tc]);
        tile[tr + rr][tc + 0] = v.x;
        tile[tr + rr][tc + 1] = v.y;
        tile[tr + rr][tc + 2] = v.z;
        tile[tr + rr][tc + 3] = v.w;
    }
    __syncthreads();
    #pragma unroll
    for (int rr = 0; rr < 64; rr += 16) {
        const int n = tr + rr;
        s16x4 o;
        #pragma unroll
        for (int j = 0; j < 4; ++j) o[j] = (short)f2bf(tile[tc + j][n]);
        *reinterpret_cast<s16x4*>(&Wt[(size_t)(n0 + n) * NN + k0 + tc]) = o;
    }
}

// ---------------- K4: C[M][N] = temp[M][K] @ Wt[N][K]^T (bf16 MFMA) ----------------
__device__ __forceinline__ void gload_lds16(const u16* gsrc, u16* lds_dst) {
    __builtin_amdgcn_global_load_lds(
        (const __attribute__((address_space(1))) void*)gsrc,
        (__attribute__((address_space(3))) void*)lds_dst,
        16, 0, 0);
}

__global__ __launch_bounds__(256) void gemm_bt_kernel(
    const u16* __restrict__ Atl,   // [M][K] bf16
    const u16* __restrict__ Btl,   // [N][K] bf16
    float* __restrict__ C)         // [M][N] f32
{
    __shared__ u16 As[BM * BK];    // [row][k]
    __shared__ u16 Bs[BN * BK];    // [col][k]

    const int tid  = threadIdx.x;
    const int wid  = tid >> 6;
    const int lane = tid & 63;
    const int lhi  = lane >> 4;    // 0..3
    const int llo  = lane & 15;    // 0..15

    // XCD-aware swizzle (grid = 1024, 1024 % 8 == 0 -> simple variant bijective)
    const int nwg = gridDim.x;
    const int cpx = nwg >> 3;
    const int swz = ((int)blockIdx.x & 7) * cpx + ((int)blockIdx.x >> 3);
    const int bm = swz >> 5;       // 32 tiles along N
    const int bn = swz & 31;

    const int tileRow = bm * BM;
    const int tileCol = bn * BN;
    const int wr = wid >> 1;       // 0..1
    const int wc = wid & 1;        // 0..1

    const int srow  = wid * 32 + (lane >> 3);   // staging source row offset within 8-row stripe start
    const int skoff = (lane & 7) * 8;           // staging source k offset

    f32x4 acc[4][4];
    #pragma unroll
    for (int m = 0; m < 4; ++m)
        #pragma unroll
        for (int n = 0; n < 4; ++n)
            acc[m][n] = (f32x4){0.f, 0.f, 0.f, 0.f};

    for (int kt = 0; kt < NN / BK; ++kt) {
        const int k0 = kt * BK;
        // ---- stage A/B tiles: 4 waves x 4 instrs each cover 128 rows x 64 k ----
        #pragma unroll
        for (int t = 0; t < 4; ++t) {
            const u16* gA = Atl + (size_t)(tileRow + srow + t * 8) * NN + k0 + skoff;
            gload_lds16(gA, &As[(wid * 32 + t * 8) * BK]);
            const u16* gB = Btl + (size_t)(tileCol + srow + t * 8) * NN + k0 + skoff;
            gload_lds16(gB, &Bs[(wid * 32 + t * 8) * BK]);
        }
        __syncthreads();   // compiler emits vmcnt(0) drain before barrier

        #pragma unroll
        for (int kk = 0; kk < BK / 32; ++kk) {
            bf16x8 af[4], bfr[4];
            #pragma unroll
            for (int m = 0; m < 4; ++m)
                af[m] = *reinterpret_cast<const bf16x8*>(
                    &As[(wr * 64 + m * 16 + llo) * BK + kk * 32 + lhi * 8]);
            #pragma unroll
            for (int n = 0; n < 4; ++n)
                bfr[n] = *reinterpret_cast<const bf16x8*>(
                    &Bs[(wc * 64 + n * 16 + llo) * BK + kk * 32 + lhi * 8]);
            #pragma unroll
            for (int m = 0; m < 4; ++m)
                #pragma unroll
                for (int n = 0; n < 4; ++n)
                    acc[m][n] = __builtin_amdgcn_mfma_f32_16x16x32_bf16(
                        af[m], bfr[n], acc[m][n], 0, 0, 0);
        }
        __syncthreads();   // all waves done reading before next overwrite
    }

    // ---- epilogue: C/D layout col=lane&15, row=(lane>>4)*4+reg ----
    #pragma unroll
    for (int m = 0; m < 4; ++m) {
        #pragma unroll
        for (int n = 0; n < 4; ++n) {
            const size_t rbase = (size_t)(tileRow + wr * 64 + m * 16 + lhi * 4) * NN
                               + tileCol + wc * 64 + n * 16 + llo;
            #pragma unroll
            for (int j = 0; j < 4; ++j)
                C[rbase + (size_t)j * NN] = acc[m][n][j];
        }
    }
}

// ---------------------------------------------------------------------------
extern "C" void kernel_launch(void* const* d_in, const int* in_sizes, int n_in,
                              void* d_out, int out_size, void* d_ws, size_t ws_size,
                              hipStream_t stream) {
    const float* A = (const float*)d_in[0];
    const float* h = (const float*)d_in[1];
    const float* W = (const float*)d_in[2];
    float* out = (float*)d_out;

    // workspace layout: inv_d (16KB) | temp bf16 (32MB) | Wt bf16 (32MB)
    float* invd = (float*)d_ws;
    u16* temp = (u16*)((char*)d_ws + 16384);
    u16* wt   = temp + (size_t)NN * NN;

    rowsum_kernel<<<NN, 256, 0, stream>>>(A, invd);
    make_temp_kernel<<<(NN * (size_t)NN) / (256 * 8), 256, 0, stream>>>(A, h, invd, temp);
    transposeW_kernel<<<(NN / 64) * (NN / 64), 256, 0, stream>>>(W, wt);
    gemm_bt_kernel<<<(NN / BM) * (NN / BN), 256, 0, stream>>>(temp, wt, out);
}

// Round 2
// 176.798 us; speedup vs baseline: 1.4378x; 1.4378x over previous
//
#include <hip/hip_runtime.h>
#include <hip/hip_bf16.h>

typedef unsigned short u16;
typedef unsigned int u32;
typedef __attribute__((ext_vector_type(8))) short bf16x8;   // 8 bf16 (4 VGPRs)
typedef __attribute__((ext_vector_type(4))) short s16x4;
typedef __attribute__((ext_vector_type(4))) float f32x4;

#define NN 4096

__device__ __forceinline__ u16 f2bf(float f) {
    union { float f; u32 u; } v; v.f = f;
    u32 r = v.u + 0x7fffu + ((v.u >> 16) & 1u);   // RNE (inputs finite)
    return (u16)(r >> 16);
}

// ---------------- K1: deg = rowsum(A); inv_d = 1/(deg+1) ----------------
__global__ void rowsum_kernel(const float* __restrict__ A, float* __restrict__ invd) {
    const int row = blockIdx.x;
    const float4* a4 = reinterpret_cast<const float4*>(A + (size_t)row * NN);
    float s = 0.f;
    #pragma unroll
    for (int i = 0; i < 4; ++i) {
        float4 v = a4[threadIdx.x + i * 256];
        s += v.x + v.y + v.z + v.w;
    }
    #pragma unroll
    for (int off = 32; off > 0; off >>= 1) s += __shfl_down(s, off, 64);
    __shared__ float ws[4];
    if ((threadIdx.x & 63) == 0) ws[threadIdx.x >> 6] = s;
    __syncthreads();
    if (threadIdx.x == 0) {
        float t = ws[0] + ws[1] + ws[2] + ws[3];
        invd[row] = 1.0f / (t + 1.0f);
    }
}

// ------- K2: temp = 0.5*h + 0.5*(A + I)*inv_d[col]  -> bf16 [M][K] -------
__global__ void make_temp_kernel(const float* __restrict__ A, const float* __restrict__ h,
                                 const float* __restrict__ invd, u16* __restrict__ T) {
    const size_t g = ((size_t)blockIdx.x * 256 + threadIdx.x) * 8;
    const int row = (int)(g >> 12);
    const int col = (int)(g & 4095);
    const float4* a4 = reinterpret_cast<const float4*>(A + g);
    const float4* h4 = reinterpret_cast<const float4*>(h + g);
    const float4* d4 = reinterpret_cast<const float4*>(invd + col);
    float4 a0 = a4[0], a1 = a4[1];
    float4 h0 = h4[0], h1 = h4[1];
    float4 dd0 = d4[0], dd1 = d4[1];
    float av[8] = {a0.x,a0.y,a0.z,a0.w,a1.x,a1.y,a1.z,a1.w};
    float hv[8] = {h0.x,h0.y,h0.z,h0.w,h1.x,h1.y,h1.z,h1.w};
    float dv[8] = {dd0.x,dd0.y,dd0.z,dd0.w,dd1.x,dd1.y,dd1.z,dd1.w};
    bf16x8 o;
    #pragma unroll
    for (int j = 0; j < 8; ++j) {
        float aa = av[j] + ((col + j == row) ? 1.0f : 0.0f);
        float t = 0.5f * hv[j] + 0.5f * aa * dv[j];
        o[j] = (short)f2bf(t);
    }
    *reinterpret_cast<bf16x8*>(T + g) = o;
}

// --------- K3: Wt[n][k] = bf16(W[k][n])  (LDS 64x64 tile transpose) ---------
__global__ void transposeW_kernel(const float* __restrict__ W, u16* __restrict__ Wt) {
    __shared__ float tile[64][65];
    const int nt = blockIdx.x & 63;
    const int kt = blockIdx.x >> 6;
    const int k0 = kt * 64, n0 = nt * 64;
    const int tr = threadIdx.x >> 4;          // 0..15
    const int tc = (threadIdx.x & 15) * 4;    // 0..60
    #pragma unroll
    for (int rr = 0; rr < 64; rr += 16) {
        float4 v = *reinterpret_cast<const float4*>(&W[(size_t)(k0 + tr + rr) * NN + n0 + tc]);
        tile[tr + rr][tc + 0] = v.x;
        tile[tr + rr][tc + 1] = v.y;
        tile[tr + rr][tc + 2] = v.z;
        tile[tr + rr][tc + 3] = v.w;
    }
    __syncthreads();
    #pragma unroll
    for (int rr = 0; rr < 64; rr += 16) {
        const int n = tr + rr;
        s16x4 o;
        #pragma unroll
        for (int j = 0; j < 4; ++j) o[j] = (short)f2bf(tile[tc + j][n]);
        *reinterpret_cast<s16x4*>(&Wt[(size_t)(n0 + n) * NN + k0 + tc]) = o;
    }
}

// ============ K4: C[M][N] = temp[M][K] @ Wt[N][K]^T (bf16 MFMA) ============
// 256x256 tile, BK=32, 4 LDS buffers, 3-deep prefetch, counted vmcnt,
// XOR col-group swizzle (read side + inverse on global source), setprio.

#define GLD16(g, l) __builtin_amdgcn_global_load_lds( \
    (const __attribute__((address_space(1))) void*)(g), \
    (__attribute__((address_space(3))) void*)(l), 16, 0, 0)

__global__ __launch_bounds__(512, 2) void gemm_kernel(
    const u16* __restrict__ Atl,   // [M][K] bf16 (temp)
    const u16* __restrict__ Btl,   // [N][K] bf16 (Wt)
    float* __restrict__ C)         // [M][N] f32
{
    __shared__ u16 S[4][2][8192];  // [buf][A=0/B=1][256 rows x 32 k]

    const int tid  = threadIdx.x;
    const int wid  = tid >> 6;     // 0..7
    const int lane = tid & 63;
    const int llo  = lane & 15;
    const int lhi  = lane >> 4;    // 0..3
    const int wr   = wid >> 2;     // 0..1  (M half: 128 rows)
    const int wc   = wid & 3;      // 0..3  (N quarter: 64 cols)

    // XCD swizzle (grid=256, 256%8==0 -> simple variant bijective)
    const int swz = ((int)blockIdx.x & 7) * 32 + ((int)blockIdx.x >> 3);
    const int bm = swz >> 4, bn = swz & 15;
    const int tileRow = bm * 256, tileCol = bn * 256;

    // ---- staging source addresses (inverse-swizzled; dest is linear) ----
    // phys LDS byte off (within S[b][x]) = i*8192 + tid*16
    //   -> row = i*128 + (tid>>2), phys colgroup = tid&3
    //   logical colgroup = (tid&3) ^ ((row>>1)&3)   (same for i=0,1: 128 = 0 mod 4 after >>1&3)
    const int r0 = tid >> 2;
    const int kc = (((tid & 3) ^ ((r0 >> 1) & 3)) << 3);
    const u16* gA0 = Atl + (size_t)(tileRow + r0) * NN + kc;
    const u16* gA1 = gA0 + (size_t)128 * NN;
    const u16* gB0 = Btl + (size_t)(tileCol + r0) * NN + kc;
    const u16* gB1 = gB0 + (size_t)128 * NN;

    // ---- swizzled ds_read element offsets (u16) within S[b][x] ----
    int offA[8], offB[4];
    #pragma unroll
    for (int m = 0; m < 8; ++m) {
        const int row = wr * 128 + m * 16 + llo;
        offA[m] = row * 32 + ((lhi ^ ((row >> 1) & 3)) << 3);
    }
    #pragma unroll
    for (int n = 0; n < 4; ++n) {
        const int row = wc * 64 + n * 16 + llo;
        offB[n] = row * 32 + ((lhi ^ ((row >> 1) & 3)) << 3);
    }

    f32x4 acc[8][4];
    #pragma unroll
    for (int m = 0; m < 8; ++m)
        #pragma unroll
        for (int n = 0; n < 4; ++n)
            acc[m][n] = (f32x4){0.f, 0.f, 0.f, 0.f};

    // ---- prologue: stage tiles 0,1,2 into buffers 0,1,2 ----
    #pragma unroll
    for (int p = 0; p < 3; ++p) {
        GLD16(gA0 + p * 32, &S[p][0][wid * 512]);
        GLD16(gA1 + p * 32, &S[p][0][4096 + wid * 512]);
        GLD16(gB0 + p * 32, &S[p][1][wid * 512]);
        GLD16(gB1 + p * 32, &S[p][1][4096 + wid * 512]);
    }
    gA0 += 96; gA1 += 96; gB0 += 96; gB1 += 96;
    asm volatile("s_waitcnt vmcnt(8)" ::: "memory");   // tile 0 landed
    __builtin_amdgcn_s_barrier();
    asm volatile("" ::: "memory");

    // ---- main loop: 128 K-steps of 32 ----
    #pragma unroll 1
    for (int t = 0; t < 128; ++t) {
        // stage tile t+3 into buffer (t+3)&3 (that buffer's reads completed
        // at step t-1, before the barrier we just crossed)
        if (t < 125) {
            const int b3 = (t + 3) & 3;
            GLD16(gA0, &S[b3][0][wid * 512]);
            GLD16(gA1, &S[b3][0][4096 + wid * 512]);
            GLD16(gB0, &S[b3][1][wid * 512]);
            GLD16(gB1, &S[b3][1][4096 + wid * 512]);
            gA0 += 32; gA1 += 32; gB0 += 32; gB1 += 32;
        }
        __builtin_amdgcn_sched_barrier(0);   // pin stage-issue before compute

        const int b = t & 3;
        const u16* sA = &S[b][0][0];
        const u16* sB = &S[b][1][0];
        bf16x8 af[8], bv[4];
        #pragma unroll
        for (int m = 0; m < 8; ++m)
            af[m] = *reinterpret_cast<const bf16x8*>(sA + offA[m]);
        #pragma unroll
        for (int n = 0; n < 4; ++n)
            bv[n] = *reinterpret_cast<const bf16x8*>(sB + offB[n]);

        __builtin_amdgcn_s_setprio(1);
        #pragma unroll
        for (int m = 0; m < 8; ++m)
            #pragma unroll
            for (int n = 0; n < 4; ++n)
                acc[m][n] = __builtin_amdgcn_mfma_f32_16x16x32_bf16(
                    af[m], bv[n], acc[m][n], 0, 0, 0);
        __builtin_amdgcn_s_setprio(0);

        // counted vmcnt: steps t and t-1 (8 instrs) may stay in flight;
        // guarantees tile t+1's stage (step t-2) has landed.
        if (t < 125)       asm volatile("s_waitcnt vmcnt(8)" ::: "memory");
        else if (t == 125) asm volatile("s_waitcnt vmcnt(4)" ::: "memory");
        else if (t == 126) asm volatile("s_waitcnt vmcnt(0)" ::: "memory");
        if (t < 127) {
            __builtin_amdgcn_s_barrier();
            asm volatile("" ::: "memory");
        }
    }

    // ---- epilogue: C/D layout col=lane&15, row=(lane>>4)*4+reg ----
    #pragma unroll
    for (int m = 0; m < 8; ++m) {
        #pragma unroll
        for (int n = 0; n < 4; ++n) {
            const size_t rbase = (size_t)(tileRow + wr * 128 + m * 16 + lhi * 4) * NN
                               + tileCol + wc * 64 + n * 16 + llo;
            #pragma unroll
            for (int j = 0; j < 4; ++j)
                C[rbase + (size_t)j * NN] = acc[m][n][j];
        }
    }
}

// ---------------------------------------------------------------------------
extern "C" void kernel_launch(void* const* d_in, const int* in_sizes, int n_in,
                              void* d_out, int out_size, void* d_ws, size_t ws_size,
                              hipStream_t stream) {
    const float* A = (const float*)d_in[0];
    const float* h = (const float*)d_in[1];
    const float* W = (const float*)d_in[2];
    float* out = (float*)d_out;

    // workspace layout: inv_d (16KB) | temp bf16 (32MB) | Wt bf16 (32MB)
    float* invd = (float*)d_ws;
    u16* temp = (u16*)((char*)d_ws + 16384);
    u16* wt   = temp + (size_t)NN * NN;

    rowsum_kernel<<<NN, 256, 0, stream>>>(A, invd);
    make_temp_kernel<<<(NN * (size_t)NN) / (256 * 8), 256, 0, stream>>>(A, h, invd, temp);
    transposeW_kernel<<<(NN / 64) * (NN / 64), 256, 0, stream>>>(W, wt);
    gemm_kernel<<<256, 512, 0, stream>>>(temp, wt, out);
}